// Round 20
// baseline (318.700 us; speedup 1.0000x reference)
//
#include <hip/hip_runtime.h>
#include <stdint.h>

#define BATCH 4096
#define DIN 1024
#define DOUT 1024
#define NC 11          // GRID_SIZE + SPLINE_ORDER
#define KD 12288       // DIN * (1 + NC)
#define NKNOTS 15      // GRID_SIZE + 2*SPLINE_ORDER + 1

typedef __bf16 bf16x8 __attribute__((ext_vector_type(8)));
typedef float f32x4 __attribute__((ext_vector_type(4)));

__device__ __forceinline__ unsigned short f2bf(float f) {
    unsigned int u = __float_as_uint(f);
    unsigned int r = (u + 0x7FFFu + ((u >> 16) & 1u)) >> 16;
    return (unsigned short)r;
}

// ---------------------------------------------------------------------------
// Build A[b,:] = [ silu(u) | bsplines(silu(u)) ] in bf16, where
// u = x[b,:] (+ sum of np split-K partial slices — fuses the previous layer's
// split-K reduce into this pass).
// ---------------------------------------------------------------------------
__global__ __launch_bounds__(256) void build_A(
    const float* __restrict__ x, const float* __restrict__ P, int np,
    const float* __restrict__ grid, unsigned short* __restrict__ A) {
    __shared__ __align__(16) unsigned short lbs[256 * NC];
    const int tid = threadIdx.x;
    const int b  = blockIdx.x >> 2;
    const int i0 = (blockIdx.x & 3) * 256;
    const int i  = i0 + tid;

    float g[NKNOTS];
#pragma unroll
    for (int j = 0; j < NKNOTS; ++j) g[j] = grid[j];

    float xv = x[(size_t)b * DIN + i];
    for (int p = 0; p < np; ++p)
        xv += P[(size_t)p * BATCH * DIN + (size_t)b * DIN + i];
    const float s = xv / (1.f + __expf(-xv));   // silu

    float bs[14];
#pragma unroll
    for (int c = 0; c < 14; ++c) bs[c] = (s >= g[c] && s < g[c + 1]) ? 1.f : 0.f;
#pragma unroll
    for (int k = 1; k <= 3; ++k) {
        const float inv = (k == 1) ? 4.f : (k == 2) ? 2.f : (4.f / 3.f);
#pragma unroll
        for (int c = 0; c < 14 - k; ++c) {
            float left  = (s - g[c]) * inv;
            float right = (g[c + k + 1] - s) * inv;
            bs[c] = left * bs[c] + right * bs[c + 1];
        }
    }

    A[(size_t)b * KD + i] = f2bf(s);
#pragma unroll
    for (int c = 0; c < NC; ++c) lbs[tid * NC + c] = f2bf(bs[c]);
    __syncthreads();

    const uint4* src = (const uint4*)lbs;
    uint4* dst = (uint4*)(A + (size_t)b * KD + DIN + (size_t)i0 * NC);
    for (int j = tid; j < 352; j += 256) dst[j] = src[j];
}

// ---------------------------------------------------------------------------
// Build W[o, :] = [ base_w[o,:] | spline_w[o,:,:]*scaler[o,:] ] in bf16
// ---------------------------------------------------------------------------
__global__ __launch_bounds__(256) void build_W(
    const float* __restrict__ base_w, const float* __restrict__ spline_w,
    const float* __restrict__ scaler, unsigned short* __restrict__ W) {
    __shared__ __align__(16) unsigned short lw[256 * NC];
    const int tid = threadIdx.x;
    const int o  = blockIdx.x >> 2;
    const int i0 = (blockIdx.x & 3) * 256;
    const int i  = i0 + tid;
    const size_t oi = (size_t)o * DIN + i;

    const float sc = scaler[oi];
    W[(size_t)o * KD + i] = f2bf(base_w[oi]);
    const float* sw = spline_w + oi * NC;
#pragma unroll
    for (int c = 0; c < NC; ++c) lw[tid * NC + c] = f2bf(sw[c] * sc);
    __syncthreads();

    const uint4* src = (const uint4*)lw;
    uint4* dst = (uint4*)(W + (size_t)o * KD + DIN + (size_t)i0 * NC);
    for (int j = tid; j < 352; j += 256) dst[j] = src[j];
}

// ---------------------------------------------------------------------------
// GEMM (split-K): C = A[4096,12288] @ W[1024,12288]^T, f32 out.
// R19 = R18's 1-barrier/K-tile schedule on a 2-blocks/CU geometry:
// BM=256, BN=128, BK=32, 256 threads = 4 waves (2m x 2n) of 128x64 each.
// LDS 48KB/block -> 2 blocks resident/CU (grid 512 = 8n x 16m x kspl4).
// Independent blocks' waves cover each other's barrier/vmcnt stalls (R5/m114
// mechanism) — same kspl, so no extra HBM Part traffic.
// LDS rows are 64B (BK=32): bank-conflict-free via 8x16B-slot XOR across
// 128B row-pairs: read slot8' = (4*(rof&1)+kcol) ^ (rof>>1) -> every 16-lane
// group hits each bank-quad exactly 2x (free). Staging pre-swizzles the
// global source (rule #21): lane l of a 1KB chunk supplies global
// (row = 16ch + 2*(l>>3) + (((l&7)^(l>>3))>>2), colslot = ((l&7)^(l>>3))&3).
// Per K-tile/wave: 12 ds_reads, 6 stage gloads (spread), 32 MFMA, one
// vmcnt(0)+barrier at the region end (stages ~a full region old).
// ---------------------------------------------------------------------------
#define BM 256
#define BN 128
#define BK 32

#define MFMA8(AF, BF, RO, FN0)                                                 \
    __builtin_amdgcn_s_setprio(1);                                             \
    _Pragma("unroll")                                                          \
    for (int fm = 0; fm < 4; ++fm)                                             \
        _Pragma("unroll")                                                      \
        for (int fn = 0; fn < 2; ++fn)                                         \
            acc[(RO) + fm][(FN0) + fn] =                                       \
                __builtin_amdgcn_mfma_f32_16x16x32_bf16(                       \
                    AF[fm], BF[(FN0) + fn], acc[(RO) + fm][(FN0) + fn], 0, 0, 0); \
    __builtin_amdgcn_s_setprio(0);

#define SBAR  __builtin_amdgcn_s_barrier()
#define SCHED __builtin_amdgcn_sched_barrier(0)

__global__ __launch_bounds__(256, 2) void gemm_kan(
    const unsigned short* __restrict__ A,
    const unsigned short* __restrict__ W,
    float* __restrict__ C, float* __restrict__ Part,
    int kspl, int ktper) {
    __shared__ unsigned short As[2 * 8192];   // [buf][256*32] = 32KB
    __shared__ unsigned short Bs[2 * 4096];   // [buf][128*32] = 16KB (48KB tot)

    const int tid  = threadIdx.x;
    const int wave = tid >> 6;
    const int lane = tid & 63;
    const int per = 16 * kspl;                   // blocks per n-tile
    const int n0  = (blockIdx.x / per) * BN;
    const int r   = blockIdx.x % per;
    const int ksp = r % kspl;
    const int m0  = (r / kspl) * BM;
    const int wm = wave >> 1;                    // 0..1
    const int wn = wave & 1;                     // 0..1

    // stage-side lane constants (pre-swizzled global source, rule #21)
    const int srow2 = lane >> 3;                 // 128B pair index in chunk
    const int sl8g  = (lane & 7) ^ srow2;        // global slot8
    const int sgrow = 2 * srow2 + (sl8g >> 2);   // row within 16-row chunk
    const int sgcol = (sl8g & 3) * 8;            // elem col within BK
    const int kbase = ksp * ktper * BK;

    f32x4 acc[8][4];
#pragma unroll
    for (int a = 0; a < 8; ++a)
#pragma unroll
        for (int b = 0; b < 4; ++b) acc[a][b] = (f32x4){0.f, 0.f, 0.f, 0.f};

    auto stageA = [&](int buf, int kt, int c) {
        const int chunk = wave * 4 + c;          // 0..15 (16-row chunks)
        const unsigned short* ga =
            A + (size_t)(m0 + chunk * 16 + sgrow) * KD + kbase + kt * BK + sgcol;
        __builtin_amdgcn_global_load_lds(
            (const __attribute__((address_space(1))) unsigned int*)ga,
            (__attribute__((address_space(3))) unsigned int*)
                &As[buf * 8192 + chunk * 512], 16, 0, 0);
    };
    auto stageB = [&](int buf, int kt, int c) {
        const int chunk = wave * 2 + c;          // 0..7
        const unsigned short* gb =
            W + (size_t)(n0 + chunk * 16 + sgrow) * KD + kbase + kt * BK + sgcol;
        __builtin_amdgcn_global_load_lds(
            (const __attribute__((address_space(1))) unsigned int*)gb,
            (__attribute__((address_space(3))) unsigned int*)
                &Bs[buf * 4096 + chunk * 512], 16, 0, 0);
    };

    // read-side lane constants: addr(elem) = Brow*32 + lanebase
    const int rof  = lane & 15;
    const int kcol = lane >> 4;                  // 0..3
    const int sl8r = (4 * (rof & 1) + kcol) ^ (rof >> 1);
    const int lanebase = (rof >> 1) * 64 + sl8r * 8;

#define LOADAF(AF, H)                                                          \
    _Pragma("unroll")                                                          \
    for (int fm = 0; fm < 4; ++fm)                                             \
        AF[fm] = *(const bf16x8*)&As[cur * 8192 +                              \
                     (wm * 128 + (H) * 64 + fm * 16) * 32 + lanebase];

#define LOADB(BF)                                                              \
    _Pragma("unroll")                                                          \
    for (int fn = 0; fn < 4; ++fn)                                             \
        BF[fn] = *(const bf16x8*)&Bs[cur * 4096 +                              \
                     (wn * 64 + fn * 16) * 32 + lanebase];

    // prologue: stage tile 0 (4A + 2B per wave); drain; publish.
    for (int c = 0; c < 4; ++c) stageA(0, 0, c);
    for (int c = 0; c < 2; ++c) stageB(0, 0, c);
    asm volatile("s_waitcnt vmcnt(0)" ::: "memory");
    SBAR;
    SCHED;

    bf16x8 af[4], bf[4];

    for (int t = 0; t < ktper; ++t) {
        const int cur = t & 1;
        const int nxt = cur ^ 1;
        const bool pf = (t + 1 < ktper);

        // H0 reads + B reads; stages spread between MFMA clusters
        LOADAF(af, 0);
        LOADB(bf);
        if (pf) { stageA(nxt, t + 1, 0); stageA(nxt, t + 1, 1); }
        MFMA8(af, bf, 0, 0);             // q1: H0 x F0
        if (pf) { stageA(nxt, t + 1, 2); stageA(nxt, t + 1, 3); }
        MFMA8(af, bf, 0, 2);             // q2: H0 x F1
        LOADAF(af, 1);
        if (pf) { stageB(nxt, t + 1, 0); stageB(nxt, t + 1, 1); }
        MFMA8(af, bf, 4, 0);             // q3: H1 x F0
        MFMA8(af, bf, 4, 2);             // q4: H1 x F1
        SCHED;
        if (pf) {
            asm volatile("s_waitcnt vmcnt(0)" ::: "memory");
            SBAR;
            SCHED;   // next tile's reads must not hoist above this point
        }
    }

    // epilogue: C/D layout col=lane&15, row=(lane>>4)*4+reg
    float* Cp = (ksp == 0) ? C : (Part + (size_t)(ksp - 1) * BATCH * DOUT);
    const int crow = (lane >> 4) * 4;
    const int ccol = lane & 15;
#pragma unroll
    for (int H = 0; H < 2; ++H)
#pragma unroll
        for (int fm = 0; fm < 4; ++fm)
#pragma unroll
            for (int fn = 0; fn < 4; ++fn) {
                const int row = m0 + wm * 128 + H * 64 + fm * 16 + crow;
                const int col = n0 + wn * 64 + fn * 16 + ccol;
#pragma unroll
                for (int rr = 0; rr < 4; ++rr)
                    Cp[(size_t)(row + rr) * DOUT + col] =
                        acc[H * 4 + fm][fn][rr];
            }
}

// ---------------------------------------------------------------------------
// X += sum of np partial slices, float4 vectorized (final layer only)
// ---------------------------------------------------------------------------
__global__ __launch_bounds__(256) void reduce_add(
    const float* __restrict__ P, float* __restrict__ X, int np) {
    const size_t i = ((size_t)blockIdx.x * 256 + threadIdx.x) * 4;
    f32x4 a = *(const f32x4*)(X + i);
    for (int p = 0; p < np; ++p)
        a = a + *(const f32x4*)(P + (size_t)p * BATCH * DOUT + i);
    *(f32x4*)(X + i) = a;
}

// ---------------------------------------------------------------------------
extern "C" void kernel_launch(void* const* d_in, const int* in_sizes, int n_in,
                              void* d_out, int out_size, void* d_ws, size_t ws_size,
                              hipStream_t stream) {
    const float* x        = (const float*)d_in[0];
    const float* base_w   = (const float*)d_in[1];
    const float* spline_w = (const float*)d_in[2];
    const float* scaler   = (const float*)d_in[3];
    const float* grid     = (const float*)d_in[4];
    float* out = (float*)d_out;

    char* ws = (char*)d_ws;
    unsigned short* Abf = (unsigned short*)ws;                       // 100,663,296 B
    unsigned short* Wbf = (unsigned short*)(ws + 100663296);         //  25,165,824 B
    float* xtmp = (float*)(ws + 100663296 + 25165824);               //  16,777,216 B
    float* Part = (float*)(ws + 100663296 + 25165824 + 16777216);    // up to 3x16.8MB

    // kspl=4 needs 3 partial buffers; fall back if scratch is short.
    const size_t base_need = 100663296u + 25165824u + 16777216u;
    const int kspl = (ws_size >= base_need + 3u * 16777216u) ? 4 : 2;
    const int ktper = (KD / BK) / kspl;

    for (int layer = 0; layer < 2; ++layer) {
        const float* xin = (layer == 0) ? x : xtmp;
        float* xout      = (layer == 0) ? xtmp : out;
        build_W<<<4096, 256, 0, stream>>>(base_w + (size_t)layer * DOUT * DIN,
                                          spline_w + (size_t)layer * DOUT * DIN * NC,
                                          scaler + (size_t)layer * DOUT * DIN, Wbf);
        // layer 1's build_A fuses the layer-0 split-K reduce (np = kspl-1)
        build_A<<<16384, 256, 0, stream>>>(xin, Part, (layer == 0) ? 0 : kspl - 1,
                                           grid, Abf);
        gemm_kan<<<128 * kspl, 256, 0, stream>>>(Abf, Wbf, xout, Part, kspl, ktper);
    }
    reduce_add<<<BATCH * DOUT / 1024, 256, 0, stream>>>(Part, out, kspl - 1);
}

// Round 21
// 274.506 us; speedup vs baseline: 1.1610x; 1.1610x over previous
//
#include <hip/hip_runtime.h>
#include <stdint.h>

#define BATCH 4096
#define DIN 1024
#define DOUT 1024
#define NC 11          // GRID_SIZE + SPLINE_ORDER
#define KD 12288       // DIN * (1 + NC)
#define NKNOTS 15      // GRID_SIZE + 2*SPLINE_ORDER + 1

typedef __bf16 bf16x8 __attribute__((ext_vector_type(8)));
typedef float f32x4 __attribute__((ext_vector_type(4)));

__device__ __forceinline__ unsigned short f2bf(float f) {
    unsigned int u = __float_as_uint(f);
    unsigned int r = (u + 0x7FFFu + ((u >> 16) & 1u)) >> 16;
    return (unsigned short)r;
}

// ---------------------------------------------------------------------------
// Build A[b,:] = [ silu(u) | bsplines(silu(u)) ] in bf16, where
// u = x[b,:] (+ sum of np split-K partial slices — fuses the previous layer's
// split-K reduce into this pass).
// ---------------------------------------------------------------------------
__global__ __launch_bounds__(256) void build_A(
    const float* __restrict__ x, const float* __restrict__ P, int np,
    const float* __restrict__ grid, unsigned short* __restrict__ A) {
    __shared__ __align__(16) unsigned short lbs[256 * NC];
    const int tid = threadIdx.x;
    const int b  = blockIdx.x >> 2;
    const int i0 = (blockIdx.x & 3) * 256;
    const int i  = i0 + tid;

    float g[NKNOTS];
#pragma unroll
    for (int j = 0; j < NKNOTS; ++j) g[j] = grid[j];

    float xv = x[(size_t)b * DIN + i];
    for (int p = 0; p < np; ++p)
        xv += P[(size_t)p * BATCH * DIN + (size_t)b * DIN + i];
    const float s = xv / (1.f + __expf(-xv));   // silu

    float bs[14];
#pragma unroll
    for (int c = 0; c < 14; ++c) bs[c] = (s >= g[c] && s < g[c + 1]) ? 1.f : 0.f;
#pragma unroll
    for (int k = 1; k <= 3; ++k) {
        const float inv = (k == 1) ? 4.f : (k == 2) ? 2.f : (4.f / 3.f);
#pragma unroll
        for (int c = 0; c < 14 - k; ++c) {
            float left  = (s - g[c]) * inv;
            float right = (g[c + k + 1] - s) * inv;
            bs[c] = left * bs[c] + right * bs[c + 1];
        }
    }

    A[(size_t)b * KD + i] = f2bf(s);
#pragma unroll
    for (int c = 0; c < NC; ++c) lbs[tid * NC + c] = f2bf(bs[c]);
    __syncthreads();

    const uint4* src = (const uint4*)lbs;
    uint4* dst = (uint4*)(A + (size_t)b * KD + DIN + (size_t)i0 * NC);
    for (int j = tid; j < 352; j += 256) dst[j] = src[j];
}

// ---------------------------------------------------------------------------
// Build W[o, :] = [ base_w[o,:] | spline_w[o,:,:]*scaler[o,:] ] in bf16
// ---------------------------------------------------------------------------
__global__ __launch_bounds__(256) void build_W(
    const float* __restrict__ base_w, const float* __restrict__ spline_w,
    const float* __restrict__ scaler, unsigned short* __restrict__ W) {
    __shared__ __align__(16) unsigned short lw[256 * NC];
    const int tid = threadIdx.x;
    const int o  = blockIdx.x >> 2;
    const int i0 = (blockIdx.x & 3) * 256;
    const int i  = i0 + tid;
    const size_t oi = (size_t)o * DIN + i;

    const float sc = scaler[oi];
    W[(size_t)o * KD + i] = f2bf(base_w[oi]);
    const float* sw = spline_w + oi * NC;
#pragma unroll
    for (int c = 0; c < NC; ++c) lw[tid * NC + c] = f2bf(sw[c] * sc);
    __syncthreads();

    const uint4* src = (const uint4*)lw;
    uint4* dst = (uint4*)(W + (size_t)o * KD + DIN + (size_t)i0 * NC);
    for (int j = tid; j < 352; j += 256) dst[j] = src[j];
}

// ---------------------------------------------------------------------------
// GEMM (split-K): C = A[4096,12288] @ W[1024,12288]^T, f32 out.
// R18 champion: ONE barrier per K-tile (the dbuf limit).
// Region t (between BAR(t) and BAR(t+1)):
//   reads a0,b0,b1 (16 ds); stage Ah0',Bh0'; MFMA q1;
//   stage Bh1'; MFMA q2; read a1 (8 ds); stage Ah1'; MFMA q3; MFMA q4;
//   W=vmcnt(0) [retires all 8 t+1 halves; youngest staged >=2 MFMA clusters
//   (~1200cy) before the wait, oldest ~4000cy -> free]; BAR.
// Safety: BAR(t) orders all waves' tile-(t-1) ds_reads (each retired before
// its consuming MFMA, which precedes BAR(t)) before tile-(t+1) stage-writes
// land in the same buffer. All tile-t reads sit after BAR(t)'s publication.
// Tail tile stages nothing and skips the trailing wait+barrier.
// Staging spread through the region (bunching costs ~10%: R9/R10). ds_reads
// are C++ loads -> compiler paces MFMA with fine-grained lgkmcnt; with no
// mid-region re-sync, wave skew lets one wave's MFMA drain cover another's
// ds_reads. T2 XOR-swizzle, n-grouped block map, setprio on MFMA clusters.
// Measured: 90.0us/dispatch, MfmaUtil 49, bank conflicts 0, 1.14 PF.
// Barrier ladder (this geometry): 8->102us, 3->96.9, 2->94.9, 1->90.0.
// ---------------------------------------------------------------------------
#define BM 256
#define BN 256
#define BK 64

#define LOADAF(AF, BASE)                                                       \
    _Pragma("unroll")                                                          \
    for (int fm = 0; fm < 4; ++fm)                                             \
        _Pragma("unroll")                                                      \
        for (int ks = 0; ks < 2; ++ks)                                         \
            AF[fm][ks] = *(const bf16x8*)&(BASE)[(wm * 64 + fm * 16 + rof) * 64 + \
                                                 (((ks * 4 + kcol) ^ xr) * 8)];

#define LOADBF(BF, BASE)                                                       \
    _Pragma("unroll")                                                          \
    for (int fn = 0; fn < 2; ++fn)                                             \
        _Pragma("unroll")                                                      \
        for (int ks = 0; ks < 2; ++ks)                                         \
            BF[fn][ks] = *(const bf16x8*)&(BASE)[(wn * 32 + fn * 16 + rof) * 64 + \
                                                 (((ks * 4 + kcol) ^ xr) * 8)];

#define MFMA16(AF, BF, RO, CO)                                                 \
    __builtin_amdgcn_s_setprio(1);                                             \
    _Pragma("unroll")                                                          \
    for (int ks = 0; ks < 2; ++ks)                                             \
        _Pragma("unroll")                                                      \
        for (int fm = 0; fm < 4; ++fm)                                         \
            _Pragma("unroll")                                                  \
            for (int fn = 0; fn < 2; ++fn)                                     \
                acc[(RO) + fm][(CO) + fn] =                                    \
                    __builtin_amdgcn_mfma_f32_16x16x32_bf16(                   \
                        AF[fm][ks], BF[fn][ks], acc[(RO) + fm][(CO) + fn], 0, 0, 0); \
    __builtin_amdgcn_s_setprio(0);

#define SBAR  __builtin_amdgcn_s_barrier()
#define SCHED __builtin_amdgcn_sched_barrier(0)

__global__ __launch_bounds__(512, 2) void gemm_kan(
    const unsigned short* __restrict__ A,
    const unsigned short* __restrict__ W,
    float* __restrict__ C, float* __restrict__ Part,
    int kspl, int ktper) {
    __shared__ unsigned short As[2 * 2 * 8192];   // [buf][half][128*64] = 64KB
    __shared__ unsigned short Bs[2 * 2 * 8192];   // 64KB (128KB total)

    const int tid  = threadIdx.x;
    const int wave = tid >> 6;
    const int lane = tid & 63;
    const int per = 16 * kspl;                   // blocks per n-tile
    const int n0  = (blockIdx.x / per) * BN;
    const int r   = blockIdx.x % per;
    const int ksp = r % kspl;
    const int m0  = (r / kspl) * BM;
    const int wm = wave >> 2;                    // 0..1
    const int wn = wave & 3;                     // 0..3

    // staging: linear LDS dest (lane*16B); global source col pre-swizzled so
    // LDS[row][c'] holds global col c' ^ ((row&7)<<4)  (T2, rule #21)
    const int srow = lane >> 3;
    const int scol = 8 * ((lane & 7) ^ (lane >> 3));
    const int kbase = ksp * ktper * BK;

    f32x4 acc[8][4];
#pragma unroll
    for (int a = 0; a < 8; ++a)
#pragma unroll
        for (int b = 0; b < 4; ++b) acc[a][b] = (f32x4){0.f, 0.f, 0.f, 0.f};

    auto stageA = [&](int buf, int h, int kt) {
        const int kk = kbase + kt * BK + scol;
#pragma unroll
        for (int c = 0; c < 2; ++c) {
            const int chunk = wave * 2 + c;      // 0..15 (8-row chunks in half)
            const unsigned short* ga =
                A + (size_t)(m0 + h * 128 + chunk * 8 + srow) * KD + kk;
            __builtin_amdgcn_global_load_lds(
                (const __attribute__((address_space(1))) unsigned int*)ga,
                (__attribute__((address_space(3))) unsigned int*)
                    &As[buf * 16384 + h * 8192 + chunk * 512], 16, 0, 0);
        }
    };
    auto stageB = [&](int buf, int h, int kt) {
        const int kk = kbase + kt * BK + scol;
#pragma unroll
        for (int c = 0; c < 2; ++c) {
            const int chunk = wave * 2 + c;
            const unsigned short* gb =
                W + (size_t)(n0 + h * 128 + chunk * 8 + srow) * KD + kk;
            __builtin_amdgcn_global_load_lds(
                (const __attribute__((address_space(1))) unsigned int*)gb,
                (__attribute__((address_space(3))) unsigned int*)
                    &Bs[buf * 16384 + h * 8192 + chunk * 512], 16, 0, 0);
        }
    };

    // prologue: stage tile 0; single free drain (loads back-to-back but only
    // once); publish.
    stageA(0, 0, 0); stageB(0, 0, 0); stageB(0, 1, 0); stageA(0, 1, 0);
    asm volatile("s_waitcnt vmcnt(0)" ::: "memory");
    SBAR;
    SCHED;

    const int rof  = lane & 15;
    const int xr   = lane & 7;
    const int kcol = lane >> 4;

    bf16x8 af[4][2], b0[2][2], b1[2][2];

    for (int t = 0; t < ktper; ++t) {
        const int cur = t & 1;
        const int nxt = cur ^ 1;
        const bool pf = (t + 1 < ktper);
        const unsigned short* Ab = &As[cur * 16384];
        const unsigned short* Bb = &Bs[cur * 16384];

        // H0 reads + early stages
        LOADAF(af, Ab);
        LOADBF(b0, Bb);
        LOADBF(b1, Bb + 8192);
        if (pf) { stageA(nxt, 0, t + 1); stageB(nxt, 0, t + 1); }
        MFMA16(af, b0, 0, 0);            // q1
        if (pf) stageB(nxt, 1, t + 1);
        MFMA16(af, b1, 0, 2);            // q2
        // H1 reads (published at BAR(t)) + last stage
        LOADAF(af, Ab + 8192);
        if (pf) stageA(nxt, 1, t + 1);
        MFMA16(af, b1, 4, 2);            // q3
        MFMA16(af, b0, 4, 0);            // q4 (register-fed)
        SCHED;
        if (pf) {
            // retire all 8 t+1 halves (youngest ~2 MFMA clusters old)
            asm volatile("s_waitcnt vmcnt(0)" ::: "memory");
            SBAR;
            SCHED;   // next tile's reads must not hoist above this point
        }
    }

    // epilogue: C/D layout col=lane&15, row=(lane>>4)*4+reg
    float* Cp = (ksp == 0) ? C : (Part + (size_t)(ksp - 1) * BATCH * DOUT);
    const int crow = (lane >> 4) * 4;
    const int ccol = lane & 15;
#pragma unroll
    for (int H = 0; H < 2; ++H)
#pragma unroll
        for (int fm = 0; fm < 4; ++fm)
#pragma unroll
            for (int F = 0; F < 2; ++F)
#pragma unroll
                for (int fn = 0; fn < 2; ++fn) {
                    const int row = m0 + H * 128 + wm * 64 + fm * 16 + crow;
                    const int col = n0 + F * 128 + wn * 32 + fn * 16 + ccol;
#pragma unroll
                    for (int rr = 0; rr < 4; ++rr)
                        Cp[(size_t)(row + rr) * DOUT + col] =
                            acc[H * 4 + fm][F * 2 + fn][rr];
                }
}

// ---------------------------------------------------------------------------
// X += sum of np partial slices, float4 vectorized (final layer only)
// ---------------------------------------------------------------------------
__global__ __launch_bounds__(256) void reduce_add(
    const float* __restrict__ P, float* __restrict__ X, int np) {
    const size_t i = ((size_t)blockIdx.x * 256 + threadIdx.x) * 4;
    f32x4 a = *(const f32x4*)(X + i);
    for (int p = 0; p < np; ++p)
        a = a + *(const f32x4*)(P + (size_t)p * BATCH * DOUT + i);
    *(f32x4*)(X + i) = a;
}

// ---------------------------------------------------------------------------
extern "C" void kernel_launch(void* const* d_in, const int* in_sizes, int n_in,
                              void* d_out, int out_size, void* d_ws, size_t ws_size,
                              hipStream_t stream) {
    const float* x        = (const float*)d_in[0];
    const float* base_w   = (const float*)d_in[1];
    const float* spline_w = (const float*)d_in[2];
    const float* scaler   = (const float*)d_in[3];
    const float* grid     = (const float*)d_in[4];
    float* out = (float*)d_out;

    char* ws = (char*)d_ws;
    unsigned short* Abf = (unsigned short*)ws;                       // 100,663,296 B
    unsigned short* Wbf = (unsigned short*)(ws + 100663296);         //  25,165,824 B
    float* xtmp = (float*)(ws + 100663296 + 25165824);               //  16,777,216 B
    float* Part = (float*)(ws + 100663296 + 25165824 + 16777216);    // up to 3x16.8MB

    // kspl=4 needs 3 partial buffers; fall back if scratch is short.
    const size_t base_need = 100663296u + 25165824u + 16777216u;
    const int kspl = (ws_size >= base_need + 3u * 16777216u) ? 4 : 2;
    const int ktper = (KD / BK) / kspl;

    for (int layer = 0; layer < 2; ++layer) {
        const float* xin = (layer == 0) ? x : xtmp;
        float* xout      = (layer == 0) ? xtmp : out;
        build_W<<<4096, 256, 0, stream>>>(base_w + (size_t)layer * DOUT * DIN,
                                          spline_w + (size_t)layer * DOUT * DIN * NC,
                                          scaler + (size_t)layer * DOUT * DIN, Wbf);
        // layer 1's build_A fuses the layer-0 split-K reduce (np = kspl-1)
        build_A<<<16384, 256, 0, stream>>>(xin, Part, (layer == 0) ? 0 : kspl - 1,
                                           grid, Abf);
        gemm_kan<<<64 * kspl, 512, 0, stream>>>(Abf, Wbf, xout, Part, kspl, ktper);
    }
    reduce_add<<<BATCH * DOUT / 1024, 256, 0, stream>>>(Part, out, kspl - 1);
}